// Round 1
// baseline (85.547 us; speedup 1.0000x reference)
//
#include <hip/hip_runtime.h>

// Problem constants (from reference): N=16, C_X=512, C_W=32, groups=16,
// H=W=64, K=3, STRIDE=1, PAD=1, DIL=1, out_h=out_w=64.
constexpr int NB   = 16;
constexpr int CX   = 512;
constexpr int CW   = 32;
constexpr int GRP  = 16;   // CX / CW
constexpr int HW   = 64;   // H == W == out_h == out_w
constexpr int PIX  = HW * HW; // 4096

// One thread per (n, c, oh, ow); loops over 16 groups.
// weight[n][c][kk][pix] read once per thread (9 loads, amortized over 16 outputs).
// input[n][g*32+c][ih][iw] read 9x per group; tap overlap served by L1/L2.
__global__ __launch_bounds__(256) void agg_kernel(
    const float* __restrict__ in,   // [16][512][64][64]
    const float* __restrict__ wt,   // [16][32][9][4096]
    float* __restrict__ out)        // [16][512][64][64]
{
    int idx = blockIdx.x * 256 + threadIdx.x;
    int ow = idx & (HW - 1);
    int oh = (idx >> 6) & (HW - 1);
    int c  = (idx >> 12) & (CW - 1);
    int n  = idx >> 17;

    int pix = oh * HW + ow;

    // Load the 9 per-pixel weights.
    const float* wp = wt + ((size_t)(n * CW + c) * 9) * PIX + pix;
    float w[9];
    #pragma unroll
    for (int kk = 0; kk < 9; ++kk) w[kk] = wp[(size_t)kk * PIX];

    // Zero out taps that fall outside the (unpadded) input. Then we can load
    // from clamped addresses unconditionally (no divergence, values * 0).
    if (oh == 0)      { w[0] = 0.f; w[1] = 0.f; w[2] = 0.f; }
    if (oh == HW - 1) { w[6] = 0.f; w[7] = 0.f; w[8] = 0.f; }
    if (ow == 0)      { w[0] = 0.f; w[3] = 0.f; w[6] = 0.f; }
    if (ow == HW - 1) { w[2] = 0.f; w[5] = 0.f; w[8] = 0.f; }

    // Precompute the 9 clamped tap offsets (group-invariant).
    int offs[9];
    #pragma unroll
    for (int i = 0; i < 3; ++i) {
        int ih = oh + i - 1;
        ih = ih < 0 ? 0 : (ih > HW - 1 ? HW - 1 : ih);
        #pragma unroll
        for (int j = 0; j < 3; ++j) {
            int iw = ow + j - 1;
            iw = iw < 0 ? 0 : (iw > HW - 1 ? HW - 1 : iw);
            offs[i * 3 + j] = ih * HW + iw;
        }
    }

    const float* ibase = in  + (size_t)(n * CX + c) * PIX;
    float*       obase = out + (size_t)(n * CX + c) * PIX + pix;

    #pragma unroll 1
    for (int g = 0; g < GRP; ++g) {
        const float* ip = ibase + (size_t)g * CW * PIX;
        float acc = 0.f;
        #pragma unroll
        for (int kk = 0; kk < 9; ++kk) {
            acc = fmaf(w[kk], ip[offs[kk]], acc);
        }
        obase[(size_t)g * CW * PIX] = acc;
    }
}

extern "C" void kernel_launch(void* const* d_in, const int* in_sizes, int n_in,
                              void* d_out, int out_size, void* d_ws, size_t ws_size,
                              hipStream_t stream) {
    const float* in = (const float*)d_in[0];   // (16, 512, 64, 64) f32
    const float* wt = (const float*)d_in[1];   // (16, 32, 9, 4096) f32
    float* out = (float*)d_out;                // (16, 512, 64, 64) f32

    const int total_threads = NB * CW * PIX;   // 2,097,152
    const int block = 256;
    const int grid = total_threads / block;    // 8192
    agg_kernel<<<grid, block, 0, stream>>>(in, wt, out);
}